// Round 4
// baseline (834.448 us; speedup 1.0000x reference)
//
#include <hip/hip_runtime.h>
#include <hip/hip_bf16.h>

// SWIN attention, round 8.
// R3 post-mortem: spill eliminated but dur unchanged -> limiter is residency
// (2 waves/SIMD) + barrier/latency serialization, not spill traffic.
// This round: 1 wave = 1 head = 1 block (64 thr).
//   - LDS 12,288 B/block -> ~13 blocks/CU -> ~3.25 waves/SIMD
//   - ZERO barriers (all LDS deps are same-wave, lgkmcnt-ordered)
//   - R0's single-sweep acc[4][6] GEMM restored (24 indep accumulators)
//   - bf16 A-reads both passes (convert kernel reinstated for pass 0);
//     grid (window, head) 2D -> co-window blocks land on the same XCD
//     (linear IDs differ by multiples of 2048) -> L2 reuse of the A tile.
//   - unchunked launcher (ws >= 128.5MB proven by S=1 in all prior rounds);
//     pass-1 window buffer aliases `out` (bf16 scratch, later overwritten).

typedef short short8 __attribute__((ext_vector_type(8)));
typedef float floatx4 __attribute__((ext_vector_type(4)));

#define SCALE 0.17677669529663687f  // 1/sqrt(32)
#define NEGM  -1e9f

__device__ __forceinline__ ushort f2b(float f) {  // RNE fp32->bf16
  uint u = __float_as_uint(f);
  return (ushort)((u + 0x7FFFu + ((u >> 16) & 1u)) >> 16);
}

__device__ __forceinline__ void win_coords(int pass, int gw, int s,
                                           int& m, int& h, int& w) {
  m = gw >> 6;
  int wy = (gw >> 3) & 7, wx = gw & 7;
  h = wy * 8 + (s >> 3);
  w = wx * 8 + (s & 7);
  if (pass) { h = (h + 4) & 63; w = (w + 4) & 63; }
}

__device__ __forceinline__ int region_id(int wy, int wx, int s) {
  int rh = (wy == 7) ? (((s >> 3) >= 4) ? 2 : 1) : 0;
  int rw = (wx == 7) ? (((s & 7) >= 4) ? 2 : 1) : 0;
  return rh * 3 + rw;
}

// ---- swizzled LDS index helpers (ushort units), verified in round 7 ----
__device__ __forceinline__ int qk_idx(int tok, int d) {
  return tok * 32 + ((((d >> 3) ^ (tok >> 2)) & 3) << 3) + (d & 7);
}
__device__ __forceinline__ int v_idx(int d, int tok) {
  return d * 64 + ((((tok >> 3) ^ d) & 7) << 3) + (tok & 7);
}
__device__ __forceinline__ int p_idx(int row, int col) {
  return row * 64 + ((((col >> 3) ^ row) & 7) << 3) + (col & 7);
}

// ---------------------------------------------------------------------------
// K0: weights -> k-contiguous bf16.
// ---------------------------------------------------------------------------
__global__ __launch_bounds__(256) void wtrans_kernel(
    const float* __restrict__ wqkv, const float* __restrict__ wo,
    ushort* __restrict__ wqkvT, ushort* __restrict__ woT) {
  const int t = threadIdx.x, b = blockIdx.x;
  if (b < 768) {
    wqkvT[b * 256 + t] = f2b(wqkv[t * 768 + b]);
  } else {
    const int n = b - 768;
    woT[n * 256 + t] = f2b(wo[t * 256 + n]);
  }
}

// ---------------------------------------------------------------------------
// K1: gather window tokens (pass-0 layout) + fp32->bf16.
// ---------------------------------------------------------------------------
__global__ __launch_bounds__(256) void convert_kernel(
    const float* __restrict__ src, ushort* __restrict__ xw) {
  const int t = threadIdx.x;
  const int row = blockIdx.x * 8 + (t >> 5);
  const int c = (t & 31) * 8;
  int m, h, w;
  win_coords(0, row >> 6, row & 63, m, h, w);
  const float* s = src + (size_t)((m * 64 + h) * 64 + w) * 256 + c;
  float4 a = *(const float4*)s;
  float4 b = *(const float4*)(s + 4);
  ushort o[8] = {f2b(a.x), f2b(a.y), f2b(a.z), f2b(a.w),
                 f2b(b.x), f2b(b.y), f2b(b.z), f2b(b.w)};
  *(uint4*)(xw + (size_t)row * 256 + c) = *(uint4*)o;
}

// ---------------------------------------------------------------------------
// K2: fused qkv + attention. grid (2048 windows, 8 heads) x 64 threads.
// One wave per block: no barriers anywhere. LDS 12,288 B:
//   Qs[2048 us] @0 | Ks[2048] @2048 | Vt[2048] @4096 ; Ps[4096] aliases Q|K.
// ---------------------------------------------------------------------------
__global__ __launch_bounds__(64) void qkvattn_kernel(
    const ushort* __restrict__ xw, const ushort* __restrict__ wqkvT,
    const float* __restrict__ bqkv, ushort* __restrict__ attn_out, int pass) {
  __shared__ ushort sm[6144];
  const int lane = threadIdx.x;
  const int quad = lane >> 4, l15 = lane & 15;
  const int wi = blockIdx.x;   // window 0..2047
  const int hh = blockIdx.y;   // head   0..7
  ushort* Qs = sm;
  ushort* Ks = sm + 2048;
  ushort* Vt = sm + 4096;
  ushort* Ps = sm;             // aliases Q|K (dead when P is written)

  const ushort* xwin = xw + (size_t)wi * 16384;

  // ---- qkv GEMM for this head: M=64 tok, N=96 (Q|K|V x 32d), K=256 ----
  floatx4 acc[4][6];
#pragma unroll
  for (int i = 0; i < 4; ++i)
#pragma unroll
    for (int j = 0; j < 6; ++j) acc[i][j] = {0.f, 0.f, 0.f, 0.f};

  const ushort* brow[6];
#pragma unroll
  for (int nt = 0; nt < 6; ++nt) {
    const int n = (nt >> 1) * 256 + hh * 32 + (nt & 1) * 16 + l15;
    brow[nt] = wqkvT + (size_t)n * 256;
  }

#pragma unroll
  for (int ks = 0; ks < 8; ++ks) {
    const int k0 = ks * 32 + quad * 8;
    short8 af[4], bf[6];
#pragma unroll
    for (int mi = 0; mi < 4; ++mi)
      af[mi] = *(const short8*)(xwin + (mi * 16 + l15) * 256 + k0);
#pragma unroll
    for (int nt = 0; nt < 6; ++nt)
      bf[nt] = *(const short8*)(brow[nt] + k0);
#pragma unroll
    for (int mi = 0; mi < 4; ++mi)
#pragma unroll
      for (int nt = 0; nt < 6; ++nt)
        acc[mi][nt] = __builtin_amdgcn_mfma_f32_16x16x32_bf16(
            af[mi], bf[nt], acc[mi][nt], 0, 0, 0);
  }

  // epilogue: +bias, bf16, into LDS (same-wave, no barrier)
#pragma unroll
  for (int nt = 0; nt < 6; ++nt) {
    const int d = (nt & 1) * 16 + l15;
    const float bias = bqkv[(nt >> 1) * 256 + hh * 32 + d];
#pragma unroll
    for (int mi = 0; mi < 4; ++mi)
#pragma unroll
      for (int r = 0; r < 4; ++r) {
        const int tok = mi * 16 + quad * 4 + r;
        const ushort v = f2b(acc[mi][nt][r] + bias);
        if (nt < 2)      Qs[qk_idx(tok, d)] = v;
        else if (nt < 4) Ks[qk_idx(tok, d)] = v;
        else             Vt[v_idx(d, tok)] = v;
      }
  }

  // ---- QK^T ----
  short8 qf[4], kf[4];
#pragma unroll
  for (int i = 0; i < 4; ++i) {
    const int row = i * 16 + l15;
    qf[i] = *(const short8*)&Qs[qk_idx(row, quad * 8)];
    kf[i] = *(const short8*)&Ks[qk_idx(row, quad * 8)];
  }
  floatx4 S[4][4];
#pragma unroll
  for (int i = 0; i < 4; ++i)
#pragma unroll
    for (int j = 0; j < 4; ++j) S[i][j] = {0.f, 0.f, 0.f, 0.f};
#pragma unroll
  for (int mi = 0; mi < 4; ++mi)
#pragma unroll
    for (int nj = 0; nj < 4; ++nj)
      S[mi][nj] = __builtin_amdgcn_mfma_f32_16x16x32_bf16(
          qf[mi], kf[nj], S[mi][nj], 0, 0, 0);

  // scale + swin mask
  const int wy = (wi >> 3) & 7, wx = wi & 7;
#pragma unroll
  for (int mi = 0; mi < 4; ++mi)
#pragma unroll
    for (int nj = 0; nj < 4; ++nj)
#pragma unroll
      for (int r = 0; r < 4; ++r) S[mi][nj][r] *= SCALE;
  if (pass) {
    int ridc[4];
#pragma unroll
    for (int nj = 0; nj < 4; ++nj) ridc[nj] = region_id(wy, wx, nj * 16 + l15);
#pragma unroll
    for (int mi = 0; mi < 4; ++mi)
#pragma unroll
      for (int r = 0; r < 4; ++r) {
        const int rr = region_id(wy, wx, mi * 16 + quad * 4 + r);
#pragma unroll
        for (int nj = 0; nj < 4; ++nj)
          if (rr != ridc[nj]) S[mi][nj][r] += NEGM;
      }
  }

  // softmax per row; write P (bf16) to Ps (aliases Q|K, both now dead)
#pragma unroll
  for (int mi = 0; mi < 4; ++mi) {
#pragma unroll
    for (int r = 0; r < 4; ++r) {
      float mx = fmaxf(fmaxf(S[mi][0][r], S[mi][1][r]),
                       fmaxf(S[mi][2][r], S[mi][3][r]));
#pragma unroll
      for (int o = 1; o < 16; o <<= 1) mx = fmaxf(mx, __shfl_xor(mx, o));
      float sm_ = 0.f;
#pragma unroll
      for (int nj = 0; nj < 4; ++nj) {
        float e = __expf(S[mi][nj][r] - mx);
        S[mi][nj][r] = e;
        sm_ += e;
      }
#pragma unroll
      for (int o = 1; o < 16; o <<= 1) sm_ += __shfl_xor(sm_, o);
      const float inv = 1.f / sm_;
      const int row = mi * 16 + quad * 4 + r;
#pragma unroll
      for (int nj = 0; nj < 4; ++nj)
        Ps[p_idx(row, nj * 16 + l15)] = f2b(S[mi][nj][r] * inv);
    }
  }

  // ---- PV: A = P (LDS), B = V^T (LDS) ----
  floatx4 O[4][2];
#pragma unroll
  for (int i = 0; i < 4; ++i) {
    O[i][0] = {0.f, 0.f, 0.f, 0.f};
    O[i][1] = {0.f, 0.f, 0.f, 0.f};
  }
#pragma unroll
  for (int ks = 0; ks < 2; ++ks) {
    short8 bfr[2];
#pragma unroll
    for (int n2 = 0; n2 < 2; ++n2)
      bfr[n2] = *(const short8*)&Vt[v_idx(n2 * 16 + l15, ks * 32 + quad * 8)];
#pragma unroll
    for (int mi = 0; mi < 4; ++mi) {
      short8 af2 = *(const short8*)&Ps[p_idx(mi * 16 + l15, ks * 32 + quad * 8)];
#pragma unroll
      for (int n2 = 0; n2 < 2; ++n2)
        O[mi][n2] = __builtin_amdgcn_mfma_f32_16x16x32_bf16(
            af2, bfr[n2], O[mi][n2], 0, 0, 0);
    }
  }

  // store bf16 [win][tok][256]
  ushort* ob = attn_out + (size_t)wi * 16384 + hh * 32;
#pragma unroll
  for (int mi = 0; mi < 4; ++mi)
#pragma unroll
    for (int r = 0; r < 4; ++r) {
      const int s = mi * 16 + quad * 4 + r;
      ob[s * 256 + l15]      = f2b(O[mi][0][r]);
      ob[s * 256 + 16 + l15] = f2b(O[mi][1][r]);
    }
}

// ---------------------------------------------------------------------------
// K3: out-proj GEMM (bf16 A). pass0: scatter bf16 into pass-1 window layout
// of xw1 (fuses window_reverse + roll + window_partition). pass1: fp32 out.
// ---------------------------------------------------------------------------
__global__ __launch_bounds__(256) void proj_mfma_kernel(
    const ushort* __restrict__ attn, const ushort* __restrict__ BT,
    const float* __restrict__ bo, float* __restrict__ out,
    ushort* __restrict__ xw1, int w0, int pass) {
  __shared__ ushort As[128][72];
  __shared__ ushort Bs[128][72];
  const int t = threadIdx.x;
  const int lane = t & 63, wv = t >> 6;
  const int wm = wv >> 1, wn = wv & 1;
  const int quad = lane >> 4, l15 = lane & 15;
  const int sr = t >> 1, sh = (t & 1) * 32;
  const int bn0 = blockIdx.x * 128, row0 = blockIdx.y * 128;

  floatx4 acc[4][4];
#pragma unroll
  for (int i = 0; i < 4; ++i)
#pragma unroll
    for (int j = 0; j < 4; ++j) acc[i][j] = {0.f, 0.f, 0.f, 0.f};

  const ushort* arow = attn + (size_t)(row0 + sr) * 256 + sh;
  const ushort* brow = BT + (size_t)(bn0 + sr) * 256 + sh;

  for (int kc = 0; kc < 4; ++kc) {
    const int k0 = kc * 64;
#pragma unroll
    for (int u = 0; u < 4; ++u) {
      *(uint4*)&As[sr][sh + u * 8] = *(const uint4*)(arow + k0 + u * 8);
      *(uint4*)&Bs[sr][sh + u * 8] = *(const uint4*)(brow + k0 + u * 8);
    }
    __syncthreads();
#pragma unroll
    for (int ks = 0; ks < 2; ++ks) {
      const int ko = ks * 32 + quad * 8;
      short8 af[4], bf[4];
#pragma unroll
      for (int i = 0; i < 4; ++i) {
        af[i] = *(const short8*)&As[wm * 64 + i * 16 + l15][ko];
        bf[i] = *(const short8*)&Bs[wn * 64 + i * 16 + l15][ko];
      }
#pragma unroll
      for (int mi = 0; mi < 4; ++mi)
#pragma unroll
        for (int nj = 0; nj < 4; ++nj)
          acc[mi][nj] = __builtin_amdgcn_mfma_f32_16x16x32_bf16(
              af[mi], bf[nj], acc[mi][nj], 0, 0, 0);
    }
    __syncthreads();
  }

  float bias[4];
  int ncol[4];
#pragma unroll
  for (int nj = 0; nj < 4; ++nj) {
    ncol[nj] = bn0 + wn * 64 + nj * 16 + l15;
    bias[nj] = bo[ncol[nj]];
  }
#pragma unroll
  for (int mi = 0; mi < 4; ++mi)
#pragma unroll
    for (int r = 0; r < 4; ++r) {
      const int gr = row0 + wm * 64 + mi * 16 + quad * 4 + r;
      int m, h, w;
      win_coords(pass, w0 + (gr >> 6), gr & 63, m, h, w);
      if (pass == 0) {
        // y[m,h,w] feeds pass-1 window token with h'=(h-4)&63, w'=(w-4)&63
        const int h2 = (h - 4) & 63, w2 = (w - 4) & 63;
        const int row2 = ((m * 64 + (h2 >> 3) * 8 + (w2 >> 3)) << 6) +
                         (h2 & 7) * 8 + (w2 & 7);
        ushort* xrow = xw1 + (size_t)row2 * 256;
#pragma unroll
        for (int nj = 0; nj < 4; ++nj)
          xrow[ncol[nj]] = f2b(acc[mi][nj][r] + bias[nj]);
      } else {
        float* orow = out + (size_t)((m * 64 + h) * 64 + w) * 256;
#pragma unroll
        for (int nj = 0; nj < 4; ++nj)
          orow[ncol[nj]] = acc[mi][nj][r] + bias[nj];
      }
    }
}

// ---------------------------------------------------------------------------
extern "C" void kernel_launch(void* const* d_in, const int* in_sizes, int n_in,
                              void* d_out, int out_size, void* d_ws, size_t ws_size,
                              hipStream_t stream) {
  (void)in_sizes; (void)n_in; (void)out_size;
  const float* x    = (const float*)d_in[0];
  const float* wqkv = (const float*)d_in[1];
  const float* bqkv = (const float*)d_in[2];
  const float* wo   = (const float*)d_in[3];
  const float* bo   = (const float*)d_in[4];
  float* out = (float*)d_out;

  // ws: wqkvT(384K) | woT(128K) | xw0 bf16 (64M) | attn bf16 (64M)
  // xw1 (pass-1 window buffer, 64M bf16): carved from ws if room, else
  // aliases `out` (safe: pass-1 proj runs strictly after all its readers
  // and overwrites every element with the final fp32 result).
  ushort* wqkvT = (ushort*)d_ws;
  ushort* woT   = (ushort*)((char*)d_ws + 393216);
  ushort* xw0   = (ushort*)((char*)d_ws + 524288);
  char* p2 = (char*)d_ws + 524288 + 67108864;
  size_t fixed = 524288 + 67108864;
  size_t rem = (ws_size > fixed) ? (ws_size - fixed) : 0;

  ushort* attnws = (ushort*)p2;            // 64M (full, unchunked)
  ushort* xw1;
  if (rem >= 2ull * 67108864) {
    xw1 = (ushort*)(p2 + 67108864);
  } else {
    xw1 = (ushort*)out;                    // rem >= 64M expected (S=1 proven)
  }

  wtrans_kernel<<<dim3(1024), dim3(256), 0, stream>>>(wqkv, wo, wqkvT, woT);
  convert_kernel<<<dim3(16384), dim3(256), 0, stream>>>(x, xw0);

  for (int pass = 0; pass < 2; ++pass) {
    const ushort* src = pass ? xw1 : xw0;
    qkvattn_kernel<<<dim3(2048, 8), dim3(64), 0, stream>>>(
        src, wqkvT, bqkv, attnws, pass);
    proj_mfma_kernel<<<dim3(2, 1024), dim3(256), 0, stream>>>(
        attnws, woT, bo, out, xw1, 0, pass);
  }
}

// Round 5
// 732.592 us; speedup vs baseline: 1.1390x; 1.1390x over previous
//
#include <hip/hip_runtime.h>
#include <hip/hip_bf16.h>

// SWIN attention, round 9.
// Five-round lesson: R0's qkvattn structure (direct global bf16 A-reads,
// acc[4][6] = 24 indep accumulators, 4-wave blocks, zero barriers) beats
// every restructuring (As-staging 213us, 3-sweep 213us, 1-wave 298us vs 183).
// Its one weakness: 59392B LDS -> 2 blocks/CU. This round = R0 verbatim with
// per-wave LDS 14848->12288B via the swizzled stride-32/64 layouts (proven
// correct in rounds 6-8) -> 49152B/block -> 3 blocks/CU -> 12 waves/CU.
// Launcher keeps R8's wins: single convert (pass-0 only), pass-0 proj
// scatters bf16 straight into pass-1's window layout, unchunked.

typedef short short8 __attribute__((ext_vector_type(8)));
typedef float floatx4 __attribute__((ext_vector_type(4)));

#define SCALE 0.17677669529663687f  // 1/sqrt(32)
#define NEGM  -1e9f

__device__ __forceinline__ ushort f2b(float f) {  // RNE fp32->bf16
  uint u = __float_as_uint(f);
  return (ushort)((u + 0x7FFFu + ((u >> 16) & 1u)) >> 16);
}

__device__ __forceinline__ void win_coords(int pass, int gw, int s,
                                           int& m, int& h, int& w) {
  m = gw >> 6;
  int wy = (gw >> 3) & 7, wx = gw & 7;
  h = wy * 8 + (s >> 3);
  w = wx * 8 + (s & 7);
  if (pass) { h = (h + 4) & 63; w = (w + 4) & 63; }
}

__device__ __forceinline__ int region_id(int wy, int wx, int s) {
  int rh = (wy == 7) ? (((s >> 3) >= 4) ? 2 : 1) : 0;
  int rw = (wx == 7) ? (((s & 7) >= 4) ? 2 : 1) : 0;
  return rh * 3 + rw;
}

// ---- swizzled LDS index helpers (ushort units), proven rounds 6-8 ----
__device__ __forceinline__ int qk_idx(int tok, int d) {
  return tok * 32 + ((((d >> 3) ^ (tok >> 2)) & 3) << 3) + (d & 7);
}
__device__ __forceinline__ int v_idx(int d, int tok) {
  return d * 64 + ((((tok >> 3) ^ d) & 7) << 3) + (tok & 7);
}
__device__ __forceinline__ int p_idx(int row, int col) {
  return row * 64 + ((((col >> 3) ^ row) & 7) << 3) + (col & 7);
}

// ---------------------------------------------------------------------------
// K0: weights -> k-contiguous bf16.
// ---------------------------------------------------------------------------
__global__ __launch_bounds__(256) void wtrans_kernel(
    const float* __restrict__ wqkv, const float* __restrict__ wo,
    ushort* __restrict__ wqkvT, ushort* __restrict__ woT) {
  const int t = threadIdx.x, b = blockIdx.x;
  if (b < 768) {
    wqkvT[b * 256 + t] = f2b(wqkv[t * 768 + b]);
  } else {
    const int n = b - 768;
    woT[n * 256 + t] = f2b(wo[t * 256 + n]);
  }
}

// ---------------------------------------------------------------------------
// K1: gather window tokens (pass-0 layout) + fp32->bf16.
// ---------------------------------------------------------------------------
__global__ __launch_bounds__(256) void convert_kernel(
    const float* __restrict__ src, ushort* __restrict__ xw) {
  const int t = threadIdx.x;
  const int row = blockIdx.x * 8 + (t >> 5);
  const int c = (t & 31) * 8;
  int m, h, w;
  win_coords(0, row >> 6, row & 63, m, h, w);
  const float* s = src + (size_t)((m * 64 + h) * 64 + w) * 256 + c;
  float4 a = *(const float4*)s;
  float4 b = *(const float4*)(s + 4);
  ushort o[8] = {f2b(a.x), f2b(a.y), f2b(a.z), f2b(a.w),
                 f2b(b.x), f2b(b.y), f2b(b.z), f2b(b.w)};
  *(uint4*)(xw + (size_t)row * 256 + c) = *(uint4*)o;
}

// ---------------------------------------------------------------------------
// K2: fused qkv + attention. grid 4096 x 256 (4 waves = heads 0-3 or 4-7 of
// one window). Wave-private LDS 6144 ushorts (12288 B):
//   Qs[2048] @0 | Ks[2048] @2048 | Vt[2048] @4096 ; Ps[4096] aliases Q|K.
// Block total 49152 B -> 3 blocks/CU. No __syncthreads anywhere.
// ---------------------------------------------------------------------------
__global__ __launch_bounds__(256, 2) void qkvattn_kernel(
    const ushort* __restrict__ xw, const ushort* __restrict__ wqkvT,
    const float* __restrict__ bqkv, ushort* __restrict__ attn_out, int pass) {
  __shared__ ushort sm[4][6144];
  const int t = threadIdx.x;
  const int wv = t >> 6, lane = t & 63;
  const int quad = lane >> 4, l15 = lane & 15;
  const int wi = blockIdx.x >> 1;
  const int hh = (blockIdx.x & 1) * 4 + wv;
  const ushort* xwin = xw + (size_t)wi * 16384;
  ushort* Qs = sm[wv];
  ushort* Ks = sm[wv] + 2048;
  ushort* Vt = sm[wv] + 4096;
  ushort* Ps = sm[wv];  // aliases Q|K (both dead once P is written)

  // ---- qkv GEMM for this head: M=64 tok, N=96 (Q|K|V x 32d), K=256 ----
  floatx4 acc[4][6];
#pragma unroll
  for (int i = 0; i < 4; ++i)
#pragma unroll
    for (int j = 0; j < 6; ++j) acc[i][j] = {0.f, 0.f, 0.f, 0.f};

  const ushort* brow[6];
#pragma unroll
  for (int nt = 0; nt < 6; ++nt) {
    const int n = (nt >> 1) * 256 + hh * 32 + (nt & 1) * 16 + l15;
    brow[nt] = wqkvT + (size_t)n * 256;
  }

#pragma unroll
  for (int ks = 0; ks < 8; ++ks) {
    const int k0 = ks * 32 + quad * 8;
    short8 af[4], bf[6];
#pragma unroll
    for (int mi = 0; mi < 4; ++mi)
      af[mi] = *(const short8*)(xwin + (mi * 16 + l15) * 256 + k0);
#pragma unroll
    for (int nt = 0; nt < 6; ++nt)
      bf[nt] = *(const short8*)(brow[nt] + k0);
#pragma unroll
    for (int mi = 0; mi < 4; ++mi)
#pragma unroll
      for (int nt = 0; nt < 6; ++nt)
        acc[mi][nt] = __builtin_amdgcn_mfma_f32_16x16x32_bf16(
            af[mi], bf[nt], acc[mi][nt], 0, 0, 0);
  }

  // epilogue: +bias, bf16, into wave-private LDS (same-wave, no barrier)
#pragma unroll
  for (int nt = 0; nt < 6; ++nt) {
    const int d = (nt & 1) * 16 + l15;
    const float bias = bqkv[(nt >> 1) * 256 + hh * 32 + d];
#pragma unroll
    for (int mi = 0; mi < 4; ++mi)
#pragma unroll
      for (int r = 0; r < 4; ++r) {
        const int tok = mi * 16 + quad * 4 + r;
        const ushort v = f2b(acc[mi][nt][r] + bias);
        if (nt < 2)      Qs[qk_idx(tok, d)] = v;
        else if (nt < 4) Ks[qk_idx(tok, d)] = v;
        else             Vt[v_idx(d, tok)] = v;
      }
  }

  // ---- QK^T ----
  short8 qf[4], kf[4];
#pragma unroll
  for (int i = 0; i < 4; ++i) {
    const int row = i * 16 + l15;
    qf[i] = *(const short8*)&Qs[qk_idx(row, quad * 8)];
    kf[i] = *(const short8*)&Ks[qk_idx(row, quad * 8)];
  }
  floatx4 S[4][4];
#pragma unroll
  for (int i = 0; i < 4; ++i)
#pragma unroll
    for (int j = 0; j < 4; ++j) S[i][j] = {0.f, 0.f, 0.f, 0.f};
#pragma unroll
  for (int mi = 0; mi < 4; ++mi)
#pragma unroll
    for (int nj = 0; nj < 4; ++nj)
      S[mi][nj] = __builtin_amdgcn_mfma_f32_16x16x32_bf16(
          qf[mi], kf[nj], S[mi][nj], 0, 0, 0);

  // scale + swin mask
  const int wy = (wi >> 3) & 7, wx = wi & 7;
#pragma unroll
  for (int mi = 0; mi < 4; ++mi)
#pragma unroll
    for (int nj = 0; nj < 4; ++nj)
#pragma unroll
      for (int r = 0; r < 4; ++r) S[mi][nj][r] *= SCALE;
  if (pass) {
    int ridc[4];
#pragma unroll
    for (int nj = 0; nj < 4; ++nj) ridc[nj] = region_id(wy, wx, nj * 16 + l15);
#pragma unroll
    for (int mi = 0; mi < 4; ++mi)
#pragma unroll
      for (int r = 0; r < 4; ++r) {
        const int rr = region_id(wy, wx, mi * 16 + quad * 4 + r);
#pragma unroll
        for (int nj = 0; nj < 4; ++nj)
          if (rr != ridc[nj]) S[mi][nj][r] += NEGM;
      }
  }

  // softmax per row; write P (bf16) to Ps (aliases Q|K, both now dead)
#pragma unroll
  for (int mi = 0; mi < 4; ++mi) {
#pragma unroll
    for (int r = 0; r < 4; ++r) {
      float mx = fmaxf(fmaxf(S[mi][0][r], S[mi][1][r]),
                       fmaxf(S[mi][2][r], S[mi][3][r]));
#pragma unroll
      for (int o = 1; o < 16; o <<= 1) mx = fmaxf(mx, __shfl_xor(mx, o));
      float sm_ = 0.f;
#pragma unroll
      for (int nj = 0; nj < 4; ++nj) {
        float e = __expf(S[mi][nj][r] - mx);
        S[mi][nj][r] = e;
        sm_ += e;
      }
#pragma unroll
      for (int o = 1; o < 16; o <<= 1) sm_ += __shfl_xor(sm_, o);
      const float inv = 1.f / sm_;
      const int row = mi * 16 + quad * 4 + r;
#pragma unroll
      for (int nj = 0; nj < 4; ++nj)
        Ps[p_idx(row, nj * 16 + l15)] = f2b(S[mi][nj][r] * inv);
    }
  }

  // ---- PV: A = P (LDS), B = V^T (LDS) ----
  floatx4 O[4][2];
#pragma unroll
  for (int i = 0; i < 4; ++i) {
    O[i][0] = {0.f, 0.f, 0.f, 0.f};
    O[i][1] = {0.f, 0.f, 0.f, 0.f};
  }
#pragma unroll
  for (int ks = 0; ks < 2; ++ks) {
    short8 bfr[2];
#pragma unroll
    for (int n2 = 0; n2 < 2; ++n2)
      bfr[n2] = *(const short8*)&Vt[v_idx(n2 * 16 + l15, ks * 32 + quad * 8)];
#pragma unroll
    for (int mi = 0; mi < 4; ++mi) {
      short8 af2 = *(const short8*)&Ps[p_idx(mi * 16 + l15, ks * 32 + quad * 8)];
#pragma unroll
      for (int n2 = 0; n2 < 2; ++n2)
        O[mi][n2] = __builtin_amdgcn_mfma_f32_16x16x32_bf16(
            af2, bfr[n2], O[mi][n2], 0, 0, 0);
    }
  }

  // store bf16 [win][tok][256]
  ushort* ob = attn_out + (size_t)wi * 16384 + hh * 32;
#pragma unroll
  for (int mi = 0; mi < 4; ++mi)
#pragma unroll
    for (int r = 0; r < 4; ++r) {
      const int s = mi * 16 + quad * 4 + r;
      ob[s * 256 + l15]      = f2b(O[mi][0][r]);
      ob[s * 256 + 16 + l15] = f2b(O[mi][1][r]);
    }
}

// ---------------------------------------------------------------------------
// K3: out-proj GEMM (bf16 A). pass0: scatter bf16 into pass-1 window layout
// of xw1 (fuses window_reverse + roll + window_partition). pass1: fp32 out.
// ---------------------------------------------------------------------------
__global__ __launch_bounds__(256) void proj_mfma_kernel(
    const ushort* __restrict__ attn, const ushort* __restrict__ BT,
    const float* __restrict__ bo, float* __restrict__ out,
    ushort* __restrict__ xw1, int pass) {
  __shared__ ushort As[128][72];
  __shared__ ushort Bs[128][72];
  const int t = threadIdx.x;
  const int lane = t & 63, wv = t >> 6;
  const int wm = wv >> 1, wn = wv & 1;
  const int quad = lane >> 4, l15 = lane & 15;
  const int sr = t >> 1, sh = (t & 1) * 32;
  const int bn0 = blockIdx.x * 128, row0 = blockIdx.y * 128;

  floatx4 acc[4][4];
#pragma unroll
  for (int i = 0; i < 4; ++i)
#pragma unroll
    for (int j = 0; j < 4; ++j) acc[i][j] = {0.f, 0.f, 0.f, 0.f};

  const ushort* arow = attn + (size_t)(row0 + sr) * 256 + sh;
  const ushort* brow = BT + (size_t)(bn0 + sr) * 256 + sh;

  for (int kc = 0; kc < 4; ++kc) {
    const int k0 = kc * 64;
#pragma unroll
    for (int u = 0; u < 4; ++u) {
      *(uint4*)&As[sr][sh + u * 8] = *(const uint4*)(arow + k0 + u * 8);
      *(uint4*)&Bs[sr][sh + u * 8] = *(const uint4*)(brow + k0 + u * 8);
    }
    __syncthreads();
#pragma unroll
    for (int ks = 0; ks < 2; ++ks) {
      const int ko = ks * 32 + quad * 8;
      short8 af[4], bf[4];
#pragma unroll
      for (int i = 0; i < 4; ++i) {
        af[i] = *(const short8*)&As[wm * 64 + i * 16 + l15][ko];
        bf[i] = *(const short8*)&Bs[wn * 64 + i * 16 + l15][ko];
      }
#pragma unroll
      for (int mi = 0; mi < 4; ++mi)
#pragma unroll
        for (int nj = 0; nj < 4; ++nj)
          acc[mi][nj] = __builtin_amdgcn_mfma_f32_16x16x32_bf16(
              af[mi], bf[nj], acc[mi][nj], 0, 0, 0);
    }
    __syncthreads();
  }

  float bias[4];
  int ncol[4];
#pragma unroll
  for (int nj = 0; nj < 4; ++nj) {
    ncol[nj] = bn0 + wn * 64 + nj * 16 + l15;
    bias[nj] = bo[ncol[nj]];
  }
#pragma unroll
  for (int mi = 0; mi < 4; ++mi)
#pragma unroll
    for (int r = 0; r < 4; ++r) {
      const int gr = row0 + wm * 64 + mi * 16 + quad * 4 + r;
      int m, h, w;
      win_coords(pass, gr >> 6, gr & 63, m, h, w);
      if (pass == 0) {
        // y[m,h,w] feeds pass-1 window token with h'=(h-4)&63, w'=(w-4)&63
        const int h2 = (h - 4) & 63, w2 = (w - 4) & 63;
        const int row2 = ((m * 64 + (h2 >> 3) * 8 + (w2 >> 3)) << 6) +
                         (h2 & 7) * 8 + (w2 & 7);
        ushort* xrow = xw1 + (size_t)row2 * 256;
#pragma unroll
        for (int nj = 0; nj < 4; ++nj)
          xrow[ncol[nj]] = f2b(acc[mi][nj][r] + bias[nj]);
      } else {
        float* orow = out + (size_t)((m * 64 + h) * 64 + w) * 256;
#pragma unroll
        for (int nj = 0; nj < 4; ++nj)
          orow[ncol[nj]] = acc[mi][nj][r] + bias[nj];
      }
    }
}

// ---------------------------------------------------------------------------
extern "C" void kernel_launch(void* const* d_in, const int* in_sizes, int n_in,
                              void* d_out, int out_size, void* d_ws, size_t ws_size,
                              hipStream_t stream) {
  (void)in_sizes; (void)n_in; (void)out_size;
  const float* x    = (const float*)d_in[0];
  const float* wqkv = (const float*)d_in[1];
  const float* bqkv = (const float*)d_in[2];
  const float* wo   = (const float*)d_in[3];
  const float* bo   = (const float*)d_in[4];
  float* out = (float*)d_out;

  // ws: wqkvT(384K) | woT(128K) | xw0 bf16 (64M) | attn bf16 (64M)
  // xw1 (pass-1 window buffer, 64M bf16): carved from ws if room, else
  // aliases `out` (safe: every element of out is rewritten by pass-1 proj,
  // which runs strictly after all xw1 readers).
  ushort* wqkvT = (ushort*)d_ws;
  ushort* woT   = (ushort*)((char*)d_ws + 393216);
  ushort* xw0   = (ushort*)((char*)d_ws + 524288);
  char* p2 = (char*)d_ws + 524288 + 67108864;
  size_t fixed = 524288 + 67108864;
  size_t rem = (ws_size > fixed) ? (ws_size - fixed) : 0;

  ushort* attnws = (ushort*)p2;  // 64M (full, unchunked)
  ushort* xw1;
  if (rem >= 2ull * 67108864) {
    xw1 = (ushort*)(p2 + 67108864);
  } else {
    xw1 = (ushort*)out;
  }

  wtrans_kernel<<<dim3(1024), dim3(256), 0, stream>>>(wqkv, wo, wqkvT, woT);
  convert_kernel<<<dim3(16384), dim3(256), 0, stream>>>(x, xw0);

  for (int pass = 0; pass < 2; ++pass) {
    const ushort* src = pass ? xw1 : xw0;
    qkvattn_kernel<<<dim3(4096), dim3(256), 0, stream>>>(
        src, wqkvT, bqkv, attnws, pass);
    proj_mfma_kernel<<<dim3(2, 1024), dim3(256), 0, stream>>>(
        attnws, woT, bo, out, xw1, pass);
  }
}

// Round 6
// 704.874 us; speedup vs baseline: 1.1838x; 1.0393x over previous
//
#include <hip/hip_runtime.h>
#include <hip/hip_bf16.h>

// SWIN attention, round 10: full per-window fusion.
// Six-round record: R0's attention core (padded LDS, acc[4][6], direct
// global bf16 A/B reads, zero barriers) is unbeaten; LDS-size/occupancy
// experiments all neutral-or-worse (residency pinned ~8 waves/CU).
// This round removes the inter-kernel waste instead: one block = one
// window = 8 waves = 8 heads. After PV, waves write their 32-col O slice
// to a shared padded LDS tile (2 barriers), then compute the out-proj
// (64x32 per wave vs woT from L2) and scatter directly:
//   pass 0 -> bf16 xw1 in pass-1 window layout (reverse+roll+partition)
//   pass 1 -> fp32 out.
// attn_out HBM round-trip (64MB w + 64MB r per pass), proj kernel, and
// its LDS staging/barriers are all deleted. xw1 gets its own ws slice
// (no out aliasing -> no intra-kernel race).

typedef short short8 __attribute__((ext_vector_type(8)));
typedef float floatx4 __attribute__((ext_vector_type(4)));

#define SCALE 0.17677669529663687f  // 1/sqrt(32)
#define NEGM  -1e9f

__device__ __forceinline__ ushort f2b(float f) {  // RNE fp32->bf16
  uint u = __float_as_uint(f);
  return (ushort)((u + 0x7FFFu + ((u >> 16) & 1u)) >> 16);
}

__device__ __forceinline__ void win_coords(int pass, int gw, int s,
                                           int& m, int& h, int& w) {
  m = gw >> 6;
  int wy = (gw >> 3) & 7, wx = gw & 7;
  h = wy * 8 + (s >> 3);
  w = wx * 8 + (s & 7);
  if (pass) { h = (h + 4) & 63; w = (w + 4) & 63; }
}

__device__ __forceinline__ int region_id(int wy, int wx, int s) {
  int rh = (wy == 7) ? (((s >> 3) >= 4) ? 2 : 1) : 0;
  int rw = (wx == 7) ? (((s & 7) >= 4) ? 2 : 1) : 0;
  return rh * 3 + rw;
}

// ---------------------------------------------------------------------------
// K0: weights -> k-contiguous bf16.
// ---------------------------------------------------------------------------
__global__ __launch_bounds__(256) void wtrans_kernel(
    const float* __restrict__ wqkv, const float* __restrict__ wo,
    ushort* __restrict__ wqkvT, ushort* __restrict__ woT) {
  const int t = threadIdx.x, b = blockIdx.x;
  if (b < 768) {
    wqkvT[b * 256 + t] = f2b(wqkv[t * 768 + b]);
  } else {
    const int n = b - 768;
    woT[n * 256 + t] = f2b(wo[t * 256 + n]);
  }
}

// ---------------------------------------------------------------------------
// K1: gather window tokens (pass-0 layout) + fp32->bf16.
// ---------------------------------------------------------------------------
__global__ __launch_bounds__(256) void convert_kernel(
    const float* __restrict__ src, ushort* __restrict__ xw) {
  const int t = threadIdx.x;
  const int row = blockIdx.x * 8 + (t >> 5);
  const int c = (t & 31) * 8;
  int m, h, w;
  win_coords(0, row >> 6, row & 63, m, h, w);
  const float* s = src + (size_t)((m * 64 + h) * 64 + w) * 256 + c;
  float4 a = *(const float4*)s;
  float4 b = *(const float4*)(s + 4);
  ushort o[8] = {f2b(a.x), f2b(a.y), f2b(a.z), f2b(a.w),
                 f2b(b.x), f2b(b.y), f2b(b.z), f2b(b.w)};
  *(uint4*)(xw + (size_t)row * 256 + c) = *(uint4*)o;
}

// ---------------------------------------------------------------------------
// K2: fused qkv + attention + out-proj. grid 2048 x 512 (8 waves = 8 heads
// of one window). Per-wave LDS region 7424 ushorts (R0 padded layout):
//   Qs[64][40] @0 | Ks[64][40] @2560 | Vt[32][72] @5120 ; Ps[64][72] = Q|K.
// Ot[64][264] (16896 us) aliases wave regions 0-2 after the PV barrier.
// Block LDS 118,784 B -> 1 block/CU (8 waves/CU, same residency as before).
// ---------------------------------------------------------------------------
__global__ __launch_bounds__(512) void fused_kernel(
    const ushort* __restrict__ xw, const ushort* __restrict__ wqkvT,
    const float* __restrict__ bqkv, const ushort* __restrict__ woT,
    const float* __restrict__ bo, float* __restrict__ out,
    ushort* __restrict__ xw1, int pass) {
  __shared__ ushort sm[8][7424];
  const int t = threadIdx.x;
  const int wv = t >> 6, lane = t & 63;
  const int quad = lane >> 4, l15 = lane & 15;
  const int wi = blockIdx.x;
  const int hh = wv;
  const ushort* xwin = xw + (size_t)wi * 16384;
  ushort* Qs = sm[wv];
  ushort* Ks = sm[wv] + 2560;
  ushort* Vt = sm[wv] + 5120;
  ushort* Ps = sm[wv];       // [64][72], aliases Q|K (dead once P written)
  ushort* Ot = &sm[0][0];    // [64][264], aliases regions 0-2 after barrier

  // ---- qkv GEMM for this head: M=64 tok, N=96 (Q|K|V x 32d), K=256 ----
  floatx4 acc[4][6];
#pragma unroll
  for (int i = 0; i < 4; ++i)
#pragma unroll
    for (int j = 0; j < 6; ++j) acc[i][j] = {0.f, 0.f, 0.f, 0.f};

  const ushort* brow[6];
#pragma unroll
  for (int nt = 0; nt < 6; ++nt) {
    const int n = (nt >> 1) * 256 + hh * 32 + (nt & 1) * 16 + l15;
    brow[nt] = wqkvT + (size_t)n * 256;
  }

#pragma unroll
  for (int ks = 0; ks < 8; ++ks) {
    const int k0 = ks * 32 + quad * 8;
    short8 af[4], bf[6];
#pragma unroll
    for (int mi = 0; mi < 4; ++mi)
      af[mi] = *(const short8*)(xwin + (mi * 16 + l15) * 256 + k0);
#pragma unroll
    for (int nt = 0; nt < 6; ++nt)
      bf[nt] = *(const short8*)(brow[nt] + k0);
#pragma unroll
    for (int mi = 0; mi < 4; ++mi)
#pragma unroll
      for (int nt = 0; nt < 6; ++nt)
        acc[mi][nt] = __builtin_amdgcn_mfma_f32_16x16x32_bf16(
            af[mi], bf[nt], acc[mi][nt], 0, 0, 0);
  }

  // epilogue: +bias, bf16, into wave-private LDS (same-wave, no barrier)
#pragma unroll
  for (int nt = 0; nt < 6; ++nt) {
    const int d = (nt & 1) * 16 + l15;
    const float bias = bqkv[(nt >> 1) * 256 + hh * 32 + d];
#pragma unroll
    for (int mi = 0; mi < 4; ++mi)
#pragma unroll
      for (int r = 0; r < 4; ++r) {
        const int tok = mi * 16 + quad * 4 + r;
        const ushort v = f2b(acc[mi][nt][r] + bias);
        if (nt < 2)      Qs[tok * 40 + d] = v;
        else if (nt < 4) Ks[tok * 40 + d] = v;
        else             Vt[d * 72 + tok] = v;
      }
  }

  // ---- QK^T ----
  short8 qf[4], kf[4];
#pragma unroll
  for (int i = 0; i < 4; ++i) {
    qf[i] = *(const short8*)&Qs[(i * 16 + l15) * 40 + quad * 8];
    kf[i] = *(const short8*)&Ks[(i * 16 + l15) * 40 + quad * 8];
  }
  floatx4 S[4][4];
#pragma unroll
  for (int i = 0; i < 4; ++i)
#pragma unroll
    for (int j = 0; j < 4; ++j) S[i][j] = {0.f, 0.f, 0.f, 0.f};
#pragma unroll
  for (int mi = 0; mi < 4; ++mi)
#pragma unroll
    for (int nj = 0; nj < 4; ++nj)
      S[mi][nj] = __builtin_amdgcn_mfma_f32_16x16x32_bf16(
          qf[mi], kf[nj], S[mi][nj], 0, 0, 0);

  // scale + swin mask
  const int wy = (wi >> 3) & 7, wx = wi & 7;
#pragma unroll
  for (int mi = 0; mi < 4; ++mi)
#pragma unroll
    for (int nj = 0; nj < 4; ++nj)
#pragma unroll
      for (int r = 0; r < 4; ++r) S[mi][nj][r] *= SCALE;
  if (pass) {
    int ridc[4];
#pragma unroll
    for (int nj = 0; nj < 4; ++nj) ridc[nj] = region_id(wy, wx, nj * 16 + l15);
#pragma unroll
    for (int mi = 0; mi < 4; ++mi)
#pragma unroll
      for (int r = 0; r < 4; ++r) {
        const int rr = region_id(wy, wx, mi * 16 + quad * 4 + r);
#pragma unroll
        for (int nj = 0; nj < 4; ++nj)
          if (rr != ridc[nj]) S[mi][nj][r] += NEGM;
      }
  }

  // softmax per row; write P (bf16) to Ps (aliases Q|K, both now dead)
#pragma unroll
  for (int mi = 0; mi < 4; ++mi) {
#pragma unroll
    for (int r = 0; r < 4; ++r) {
      float mx = fmaxf(fmaxf(S[mi][0][r], S[mi][1][r]),
                       fmaxf(S[mi][2][r], S[mi][3][r]));
#pragma unroll
      for (int o = 1; o < 16; o <<= 1) mx = fmaxf(mx, __shfl_xor(mx, o));
      float sm_ = 0.f;
#pragma unroll
      for (int nj = 0; nj < 4; ++nj) {
        float e = __expf(S[mi][nj][r] - mx);
        S[mi][nj][r] = e;
        sm_ += e;
      }
#pragma unroll
      for (int o = 1; o < 16; o <<= 1) sm_ += __shfl_xor(sm_, o);
      const float inv = 1.f / sm_;
      const int row = mi * 16 + quad * 4 + r;
#pragma unroll
      for (int nj = 0; nj < 4; ++nj)
        Ps[row * 72 + nj * 16 + l15] = f2b(S[mi][nj][r] * inv);
    }
  }

  // ---- PV: A = P (LDS), B = V^T (LDS) ----
  floatx4 O[4][2];
#pragma unroll
  for (int i = 0; i < 4; ++i) {
    O[i][0] = {0.f, 0.f, 0.f, 0.f};
    O[i][1] = {0.f, 0.f, 0.f, 0.f};
  }
#pragma unroll
  for (int ks = 0; ks < 2; ++ks) {
    short8 bfr[2];
#pragma unroll
    for (int n2 = 0; n2 < 2; ++n2)
      bfr[n2] = *(const short8*)&Vt[(n2 * 16 + l15) * 72 + ks * 32 + quad * 8];
#pragma unroll
    for (int mi = 0; mi < 4; ++mi) {
      short8 af2 = *(const short8*)&Ps[(mi * 16 + l15) * 72 + ks * 32 + quad * 8];
#pragma unroll
      for (int n2 = 0; n2 < 2; ++n2)
        O[mi][n2] = __builtin_amdgcn_mfma_f32_16x16x32_bf16(
            af2, bfr[n2], O[mi][n2], 0, 0, 0);
    }
  }

  // ---- deposit O slice (cols hh*32..hh*32+31) into shared padded Ot ----
  __syncthreads();  // all waves' P/V reads complete; Ot may alias them now
#pragma unroll
  for (int mi = 0; mi < 4; ++mi)
#pragma unroll
    for (int r = 0; r < 4; ++r) {
      const int s = mi * 16 + quad * 4 + r;
      Ot[s * 264 + hh * 32 + l15]      = f2b(O[mi][0][r]);
      Ot[s * 264 + hh * 32 + 16 + l15] = f2b(O[mi][1][r]);
    }
  __syncthreads();  // Ot fully written

  // ---- out-proj: this wave computes out cols hh*32..hh*32+31, K=256 ----
  floatx4 acc2[4][2];
#pragma unroll
  for (int i = 0; i < 4; ++i) {
    acc2[i][0] = {0.f, 0.f, 0.f, 0.f};
    acc2[i][1] = {0.f, 0.f, 0.f, 0.f};
  }
  const ushort* w0row = woT + (size_t)(hh * 32 + l15) * 256;
  const ushort* w1row = w0row + 16 * 256;
#pragma unroll
  for (int ks = 0; ks < 8; ++ks) {
    const int k0 = ks * 32 + quad * 8;
    short8 bf0 = *(const short8*)(w0row + k0);
    short8 bf1 = *(const short8*)(w1row + k0);
    short8 af3[4];
#pragma unroll
    for (int mi = 0; mi < 4; ++mi)
      af3[mi] = *(const short8*)&Ot[(mi * 16 + l15) * 264 + k0];
#pragma unroll
    for (int mi = 0; mi < 4; ++mi) {
      acc2[mi][0] = __builtin_amdgcn_mfma_f32_16x16x32_bf16(
          af3[mi], bf0, acc2[mi][0], 0, 0, 0);
      acc2[mi][1] = __builtin_amdgcn_mfma_f32_16x16x32_bf16(
          af3[mi], bf1, acc2[mi][1], 0, 0, 0);
    }
  }

  // ---- epilogue: bias + scatter ----
  const float bias0 = bo[hh * 32 + l15];
  const float bias1 = bo[hh * 32 + 16 + l15];
#pragma unroll
  for (int mi = 0; mi < 4; ++mi)
#pragma unroll
    for (int r = 0; r < 4; ++r) {
      const int s = mi * 16 + quad * 4 + r;
      int m, h, w;
      win_coords(pass, wi, s, m, h, w);
      if (pass == 0) {
        // y[m,h,w] feeds pass-1 window token with h'=(h-4)&63, w'=(w-4)&63
        const int h2 = (h - 4) & 63, w2 = (w - 4) & 63;
        const int row2 = ((m * 64 + (h2 >> 3) * 8 + (w2 >> 3)) << 6) +
                         (h2 & 7) * 8 + (w2 & 7);
        ushort* xrow = xw1 + (size_t)row2 * 256;
        xrow[hh * 32 + l15]      = f2b(acc2[mi][0][r] + bias0);
        xrow[hh * 32 + 16 + l15] = f2b(acc2[mi][1][r] + bias1);
      } else {
        float* orow = out + (size_t)((m * 64 + h) * 64 + w) * 256;
        orow[hh * 32 + l15]      = acc2[mi][0][r] + bias0;
        orow[hh * 32 + 16 + l15] = acc2[mi][1][r] + bias1;
      }
    }
}

// ---------------------------------------------------------------------------
extern "C" void kernel_launch(void* const* d_in, const int* in_sizes, int n_in,
                              void* d_out, int out_size, void* d_ws, size_t ws_size,
                              hipStream_t stream) {
  (void)in_sizes; (void)n_in; (void)out_size; (void)ws_size;
  const float* x    = (const float*)d_in[0];
  const float* wqkv = (const float*)d_in[1];
  const float* bqkv = (const float*)d_in[2];
  const float* wo   = (const float*)d_in[3];
  const float* bo   = (const float*)d_in[4];
  float* out = (float*)d_out;

  // ws: wqkvT(384K) | woT(128K) | xw0 bf16 (64M) | xw1 bf16 (64M) = 128.5M
  // (ws >= 128.5M proven: every prior round selected S=1, which required
  //  rem >= 64M beyond the same 64.5M fixed prefix.)
  ushort* wqkvT = (ushort*)d_ws;
  ushort* woT   = (ushort*)((char*)d_ws + 393216);
  ushort* xw0   = (ushort*)((char*)d_ws + 524288);
  ushort* xw1   = (ushort*)((char*)d_ws + 524288 + 67108864);

  wtrans_kernel<<<dim3(1024), dim3(256), 0, stream>>>(wqkv, wo, wqkvT, woT);
  convert_kernel<<<dim3(16384), dim3(256), 0, stream>>>(x, xw0);

  fused_kernel<<<dim3(2048), dim3(512), 0, stream>>>(
      xw0, wqkvT, bqkv, woT, bo, out, xw1, 0);
  fused_kernel<<<dim3(2048), dim3(512), 0, stream>>>(
      xw1, wqkvT, bqkv, woT, bo, out, xw1, 1);
}